// Round 8
// baseline (98.600 us; speedup 1.0000x reference)
//
#include <hip/hip_runtime.h>

// B=16, C=3, H=256, W=256 fp32. 48 slices of 256x256.
// out = inverted, per-slice max-normalized, per-channel-weighted exact EDT.
//
// Pipeline (2 launches):
//   K12: per 16-col strip (768 blocks, XCD-swizzled so a slice's 16 blocks
//        share an XCD's L2): block ballots its slice's zero-mask directly from
//        the input (redundant per strip, but L2/L3-absorbed); g^2 in-LDS via
//        clz/ctz nearest-zero; +-8 windowed min-plus (min <= 80 certifies
//        exactness; per-pixel full-column fallback otherwise -> unconditionally
//        exact). Writes d2 into out (L2-resident round trip) + strip max.
//   K3:  reads d2 (L2-hot) + 16 strip maxes -> slice max; epilogue
//        out = (mx - w*sqrt(d2))/mx.
//
// Post-mortem notes:
//   R5: cooperative grid.sync() over 768 blocks costs ~45 us (cross-XCD) — never.
//   R6: recomputing the VALU-heavy window pass to skip the d2 round trip lost
//       5+ us; the 12.6 MB d2 intermediate lives in L2 and is nearly free.
//   R7: halving the window VALU was invisible — harness fills dominate.

#define PADV 1e30f

// ---------------- K12: ballots + g2 + exact min-plus, fused ----------------
// Block = 256 threads = one slice's 16-col strip.
// Swizzle: r=bx&7 (XCD), c=bx>>3; strip=c&15; slice=(c>>4)*8+r  -> all 16
// strips of a slice land on the same XCD (dispatch round-robins bx%8).
__global__ __launch_bounds__(256) void k12_colpass(const float* __restrict__ in,
                                                   float* __restrict__ d2out,
                                                   float* __restrict__ stripmax) {
    __shared__ unsigned long long bm[1024];   // [row*4 + cc]
    __shared__ float tile[16 * 273];          // row r at tile[c*273 + 8 + r]
    __shared__ float wm[4];
    int bx = blockIdx.x;
    int xr = bx & 7;
    int cc_ = bx >> 3;
    int strip = cc_ & 15;
    int slice = (cc_ >> 4) * 8 + xr;
    int w0 = strip * 16;
    int tid = threadIdx.x;
    int wave = tid >> 6;
    int lane = tid & 63;

    // ---- ballot phase: wave w handles rows w*64 .. w*64+63 ----
    {
        const float4* in4 = (const float4*)(in + (long)slice * 65536);
        #pragma unroll 8
        for (int i = 0; i < 64; ++i) {
            int r = wave * 64 + i;
            float4 v = in4[r * 64 + lane];
            unsigned long long b0 = __ballot(v.x == 0.f);
            unsigned long long b1 = __ballot(v.y == 0.f);
            unsigned long long b2 = __ballot(v.z == 0.f);
            unsigned long long b3 = __ballot(v.w == 0.f);
            if (lane == 0) {
                ulonglong4* dst = (ulonglong4*)(bm + r * 4);
                ulonglong4 u; u.x = b0; u.y = b1; u.z = b2; u.w = b3;
                *dst = u;
            }
        }
    }
    // pad rows: tile idx 0..7 (rows -8..-1) and 264..271 (rows 256..263)
    {
        int c = tid >> 4, i = tid & 15;
        tile[c * 273 + (i < 8 ? i : 256 + i)] = PADV;
    }
    __syncthreads();

    int c = tid & 15;                 // column within strip
    int p = w0 + c;                   // global column 0..255
    int rg = tid >> 4;                // 0..15

    // nearest-zero squared distance for (row, col p) from LDS bitmask
    auto nz2 = [&](int row) -> float {
        int dist = 512;               // BIG cap (H+W), matches reference
        #pragma unroll
        for (int cc = 0; cc < 4; ++cc) {
            unsigned long long M = bm[row * 4 + cc];
            int q = p - cc;                          // >= -3
            int qa = (q < 0) ? 0 : q;
            int tp = qa >> 2;                        // floor(q/4) for q>=0
            unsigned long long Ml = (q >= 0) ? (M & (~0ull >> (63 - tp))) : 0ull;
            int tn = (q < 0) ? 0 : ((q + 3) >> 2);   // ceil(q/4)
            unsigned long long Mh = (tn < 64) ? (M & (~0ull << tn)) : 0ull;
            if (Ml) dist = min(dist, q - 4 * (63 - __builtin_clzll(Ml)));
            if (Mh) dist = min(dist, 4 * __builtin_ctzll(Mh) - q);
        }
        float fd = (float)dist;
        return fd * fd;
    };

    // g2 for 16 rows each (strided rows -> small LDS write alias, cheap)
    #pragma unroll
    for (int k = 0; k < 16; ++k) {
        int r = rg + 16 * k;
        tile[c * 273 + 8 + r] = nz2(r);
    }
    __syncthreads();

    // window pass (+-8): contiguous ownership rows r0..r0+15
    int r0 = rg * 16;
    float s[32];                       // rows r0-8 .. r0+23 of column c
    #pragma unroll
    for (int i = 0; i < 32; ++i) s[i] = tile[c * 273 + r0 + i];

    float dmin[16];
    #pragma unroll
    for (int k = 0; k < 16; ++k) dmin[k] = s[k + 8];    // o = 0
    #pragma unroll
    for (int o = -8; o <= 8; ++o) {
        if (o == 0) continue;
        float oo = (float)(o * o);
        #pragma unroll
        for (int k = 0; k < 16; ++k)
            dmin[k] = fminf(dmin[k], s[k + 8 + o] + oo);
    }

    // per-pixel exact fallback: windowed min > 80 can't certify optimality
    // within +-8 (excluded candidates >= 81); rescan full column in LDS.
    // Never taken for random masks -> execz-skipped.
    #pragma unroll
    for (int k = 0; k < 16; ++k) {
        if (dmin[k] > 80.0f) {
            float best = dmin[k];
            int r = r0 + k;
            for (int rp = 0; rp < 256; ++rp) {
                float dr = (float)(r - rp);
                best = fminf(best, fmaf(dr, dr, tile[c * 273 + 8 + rp]));
            }
            dmin[k] = best;
        }
    }

    // write back d2 (L2-resident; K3 consumes immediately), track block max
    float* dst = d2out + (long)slice * 65536 + w0 + c;
    float m = 0.f;
    #pragma unroll
    for (int k = 0; k < 16; ++k) {
        dst[(long)(r0 + k) * 256] = dmin[k];
        m = fmaxf(m, dmin[k]);
    }
    #pragma unroll
    for (int off = 32; off >= 1; off >>= 1)
        m = fmaxf(m, __shfl_down(m, off, 64));
    if ((tid & 63) == 0) wm[tid >> 6] = m;
    __syncthreads();
    if (tid == 0)
        stripmax[slice * 16 + strip] = fmaxf(fmaxf(wm[0], wm[1]), fmaxf(wm[2], wm[3]));
}

// ---------------- K3: epilogue ---------------------------------------------
// 64 blocks per slice; each block reduces the slice's 16 strip maxes once.
__global__ __launch_bounds__(256) void k3_final(float* __restrict__ out,
                                                const float* __restrict__ stripmax) {
    __shared__ float sMx;
    int tid = threadIdx.x;
    int idx4 = blockIdx.x * 256 + tid;    // float4 index, 786432 total
    int slice = blockIdx.x >> 6;          // 64 blocks per slice
    if (tid < 16) {
        float v = stripmax[slice * 16 + tid];
        #pragma unroll
        for (int off = 8; off >= 1; off >>= 1) v = fmaxf(v, __shfl_down(v, off, 64));
        if (tid == 0) sMx = v;
    }
    __syncthreads();

    int c = slice % 3;
    float wgt = (c == 0) ? 0.5f : ((c == 1) ? 1.0f : 2.0f);
    float mx = wgt * __builtin_sqrtf(sMx);

    float4 d2 = ((float4*)out)[idx4];
    float4 r;
    if (mx > 0.f) {
        float inv = 1.0f / mx;
        r.x = (mx - wgt * __builtin_sqrtf(d2.x)) * inv;
        r.y = (mx - wgt * __builtin_sqrtf(d2.y)) * inv;
        r.z = (mx - wgt * __builtin_sqrtf(d2.z)) * inv;
        r.w = (mx - wgt * __builtin_sqrtf(d2.w)) * inv;
    } else {
        r.x = wgt * __builtin_sqrtf(d2.x);
        r.y = wgt * __builtin_sqrtf(d2.y);
        r.z = wgt * __builtin_sqrtf(d2.z);
        r.w = wgt * __builtin_sqrtf(d2.w);
    }
    ((float4*)out)[idx4] = r;
}

extern "C" void kernel_launch(void* const* d_in, const int* in_sizes, int n_in,
                              void* d_out, int out_size, void* d_ws, size_t ws_size,
                              hipStream_t stream) {
    const float* in = (const float*)d_in[0];
    float* out = (float*)d_out;
    float* stripmax = (float*)d_ws;       // 768 floats

    k12_colpass<<<768, 256, 0, stream>>>(in, out, stripmax);  // d2 in place in out
    k3_final<<<3072, 256, 0, stream>>>(out, stripmax);        // 786432 float4
}

// Round 9
// 83.445 us; speedup vs baseline: 1.1816x; 1.1816x over previous
//
#include <hip/hip_runtime.h>

// B=16, C=3, H=256, W=256 fp32. 48 slices of 256x256.
// out = inverted, per-slice max-normalized, per-channel-weighted exact EDT.
//
// Pipeline (3 launches — R4/R7 structure, the measured best @ ~83.0 us):
//   K1: wave per row -> four 64-bit zero-ballots per row (32 B/row) into d_ws.
//   K2: per 16-col strip: slice bitmask (8 KB) -> LDS; g^2 in-LDS via clz/ctz;
//       +-8 windowed min-plus (windowed min <= 80 certifies exactness: any
//       |o|>=9 candidate >= 81; per-pixel full-column fallback otherwise ->
//       unconditionally exact). Writes d2 (L2-resident round trip) + strip max.
//   K3: reads d2 (L2-hot) + 16 strip maxes -> slice max; epilogue
//       out = (mx - w*sqrt(d2))/mx.
//
// Post-mortem notes (why this exact structure):
//   R5: cooperative grid.sync() over 768 blocks costs ~45 us (cross-XCD) — never.
//   R6: recomputing the VALU-heavy window pass to skip the d2 round trip lost
//       5+ us; the 12.6 MB d2 intermediate lives in L2 and is nearly free.
//   R7: halving the window VALU was invisible — harness fills dominate.
//   R8: fusing K1 into K2 (16x redundant ballot phase) made K12 45 us —
//       load+ballot chains are latency-bound; never recompute a load phase.

#define PADV 1e30f

// ---------------- K1: row bitmask via ballots -------------------------------
// One wave per row. Lane l holds cols 4l..4l+3; b_cc bit l = (col 4l+cc == 0).
__global__ __launch_bounds__(256) void k1_bitmask(const float* __restrict__ in,
                                                  unsigned long long* __restrict__ bits) {
    int row = blockIdx.x * 4 + (threadIdx.x >> 6);
    int lane = threadIdx.x & 63;
    const float4 m = ((const float4*)in)[(long)row * 64 + lane];

    unsigned long long b0 = __ballot(m.x == 0.f);
    unsigned long long b1 = __ballot(m.y == 0.f);
    unsigned long long b2 = __ballot(m.z == 0.f);
    unsigned long long b3 = __ballot(m.w == 0.f);
    if (lane == 0) {
        ulonglong4* dst = (ulonglong4*)(bits + (long)row * 4);
        ulonglong4 v; v.x = b0; v.y = b1; v.z = b2; v.w = b3;
        *dst = v;
    }
}

// ---------------- K2: g2 from bitmask + exact min-plus column pass ----------
// Block = 256 threads = one slice's 16-col strip (grid 48*16).
// LDS: slice bitmask (8 KB) + column-major g2 tile, stride 273 (odd -> 2-way
// max bank alias on the hot reads, free) with 8 pad rows each side.
__global__ __launch_bounds__(256) void k2_colpass(const unsigned long long* __restrict__ bits,
                                                  float* __restrict__ d2out,
                                                  float* __restrict__ stripmax) {
    __shared__ unsigned long long bm[1024];   // [row*4 + cc]
    __shared__ float tile[16 * 273];          // row r at tile[c*273 + 8 + r]
    __shared__ float wm[4];
    int bx = blockIdx.x;
    int slice = bx >> 4;
    int w0 = (bx & 15) * 16;
    int tid = threadIdx.x;

    // load slice bitmask: 1024 ull, coalesced
    {
        const unsigned long long* src = bits + (long)slice * 1024;
        #pragma unroll
        for (int i = 0; i < 4; ++i) bm[i * 256 + tid] = src[i * 256 + tid];
    }
    // pad rows: tile idx 0..7 (rows -8..-1) and 264..271 (rows 256..263)
    {
        int c = tid >> 4, i = tid & 15;
        tile[c * 273 + (i < 8 ? i : 256 + i)] = PADV;
    }
    __syncthreads();

    int c = tid & 15;                 // column within strip
    int p = w0 + c;                   // global column 0..255
    int rg = tid >> 4;                // 0..15

    // nearest-zero squared distance for (row, col p) from LDS bitmask
    auto nz2 = [&](int row) -> float {
        int dist = 512;               // BIG cap (H+W), matches reference
        #pragma unroll
        for (int cc = 0; cc < 4; ++cc) {
            unsigned long long M = bm[row * 4 + cc];
            int q = p - cc;                          // >= -3
            int qa = (q < 0) ? 0 : q;
            int tp = qa >> 2;                        // floor(q/4) for q>=0
            unsigned long long Ml = (q >= 0) ? (M & (~0ull >> (63 - tp))) : 0ull;
            int tn = (q < 0) ? 0 : ((q + 3) >> 2);   // ceil(q/4)
            unsigned long long Mh = (tn < 64) ? (M & (~0ull << tn)) : 0ull;
            if (Ml) dist = min(dist, q - 4 * (63 - __builtin_clzll(Ml)));
            if (Mh) dist = min(dist, 4 * __builtin_ctzll(Mh) - q);
        }
        float fd = (float)dist;
        return fd * fd;
    };

    // g2 for 16 rows each (strided rows -> small LDS write alias, cheap)
    #pragma unroll
    for (int k = 0; k < 16; ++k) {
        int r = rg + 16 * k;
        tile[c * 273 + 8 + r] = nz2(r);
    }
    __syncthreads();

    // window pass (+-8): contiguous ownership rows r0..r0+15
    int r0 = rg * 16;
    float s[32];                       // rows r0-8 .. r0+23 of column c
    #pragma unroll
    for (int i = 0; i < 32; ++i) s[i] = tile[c * 273 + r0 + i];

    float dmin[16];
    #pragma unroll
    for (int k = 0; k < 16; ++k) dmin[k] = s[k + 8];    // o = 0
    #pragma unroll
    for (int o = -8; o <= 8; ++o) {
        if (o == 0) continue;
        float oo = (float)(o * o);
        #pragma unroll
        for (int k = 0; k < 16; ++k)
            dmin[k] = fminf(dmin[k], s[k + 8 + o] + oo);
    }

    // per-pixel exact fallback: windowed min > 80 can't certify optimality
    // within +-8 (excluded candidates >= 81); rescan full column in LDS.
    // Never taken for random masks -> execz-skipped.
    #pragma unroll
    for (int k = 0; k < 16; ++k) {
        if (dmin[k] > 80.0f) {
            float best = dmin[k];
            int r = r0 + k;
            for (int rp = 0; rp < 256; ++rp) {
                float dr = (float)(r - rp);
                best = fminf(best, fmaf(dr, dr, tile[c * 273 + 8 + rp]));
            }
            dmin[k] = best;
        }
    }

    // write back d2 (L2-resident; K3 consumes immediately), track block max
    float* dst = d2out + (long)slice * 65536 + w0 + c;
    float m = 0.f;
    #pragma unroll
    for (int k = 0; k < 16; ++k) {
        dst[(long)(r0 + k) * 256] = dmin[k];
        m = fmaxf(m, dmin[k]);
    }
    #pragma unroll
    for (int off = 32; off >= 1; off >>= 1)
        m = fmaxf(m, __shfl_down(m, off, 64));
    if ((tid & 63) == 0) wm[tid >> 6] = m;
    __syncthreads();
    if (tid == 0)
        stripmax[bx] = fmaxf(fmaxf(wm[0], wm[1]), fmaxf(wm[2], wm[3]));
}

// ---------------- K3: epilogue ---------------------------------------------
// 64 blocks per slice; each block reduces the slice's 16 strip maxes once.
__global__ __launch_bounds__(256) void k3_final(float* __restrict__ out,
                                                const float* __restrict__ stripmax) {
    __shared__ float sMx;
    int tid = threadIdx.x;
    int idx4 = blockIdx.x * 256 + tid;    // float4 index, 786432 total
    int slice = blockIdx.x >> 6;          // 64 blocks per slice
    if (tid < 16) {
        float v = stripmax[slice * 16 + tid];
        #pragma unroll
        for (int off = 8; off >= 1; off >>= 1) v = fmaxf(v, __shfl_down(v, off, 64));
        if (tid == 0) sMx = v;
    }
    __syncthreads();

    int c = slice % 3;
    float wgt = (c == 0) ? 0.5f : ((c == 1) ? 1.0f : 2.0f);
    float mx = wgt * __builtin_sqrtf(sMx);

    float4 d2 = ((float4*)out)[idx4];
    float4 r;
    if (mx > 0.f) {
        float inv = 1.0f / mx;
        r.x = (mx - wgt * __builtin_sqrtf(d2.x)) * inv;
        r.y = (mx - wgt * __builtin_sqrtf(d2.y)) * inv;
        r.z = (mx - wgt * __builtin_sqrtf(d2.z)) * inv;
        r.w = (mx - wgt * __builtin_sqrtf(d2.w)) * inv;
    } else {
        r.x = wgt * __builtin_sqrtf(d2.x);
        r.y = wgt * __builtin_sqrtf(d2.y);
        r.z = wgt * __builtin_sqrtf(d2.z);
        r.w = wgt * __builtin_sqrtf(d2.w);
    }
    ((float4*)out)[idx4] = r;
}

extern "C" void kernel_launch(void* const* d_in, const int* in_sizes, int n_in,
                              void* d_out, int out_size, void* d_ws, size_t ws_size,
                              hipStream_t stream) {
    const float* in = (const float*)d_in[0];
    float* out = (float*)d_out;
    float* stripmax = (float*)d_ws;                                        // 768 floats
    unsigned long long* bits = (unsigned long long*)((char*)d_ws + 4096);  // 384 KB

    k1_bitmask<<<3072, 256, 0, stream>>>(in, bits);       // 12288 rows, wave/row
    k2_colpass<<<768, 256, 0, stream>>>(bits, out, stripmax);  // d2 in place in out
    k3_final<<<3072, 256, 0, stream>>>(out, stripmax);    // 786432 float4
}